// Round 16
// baseline (355.772 us; speedup 1.0000x reference)
//
#include <hip/hip_runtime.h>
#include <hip/hip_bf16.h>
#include <stdint.h>

#define NPTS 32768
#define KNBR 32
#define NEDGES (NPTS * KNBR)
#define TM 128          // edges per block (= 4 output rows), 512 threads / 8 waves
#define AGG_STRIDE 40   // bf16 elems per agg row (80 B)
#define H_STRIDE 264    // bf16 elems per h row (528 B = 33 x 16B slots)

typedef __attribute__((ext_vector_type(8))) short short8;
typedef __attribute__((ext_vector_type(4))) float f32x4;
typedef __attribute__((ext_vector_type(2))) float f32x2;
typedef __attribute__((ext_vector_type(4))) unsigned int u32x4;
typedef __attribute__((ext_vector_type(2))) unsigned int u32x2;

// round-to-nearest-even f32 -> bf16 (one-time pack kernel only)
__device__ __forceinline__ unsigned short f2bf(float f) {
    unsigned int u = __float_as_uint(f);
    unsigned int r = (u + 0x7FFFu + ((u >> 16) & 1u)) >> 16;
    return (unsigned short)r;
}

// gfx950 packed f32->bf16 (RNE), single instruction (proven)
__device__ __forceinline__ unsigned int cvt_pk_bf16(float lo, float hi) {
    unsigned int r;
    asm("v_cvt_pk_bf16_f32 %0, %1, %2" : "=v"(r) : "v"(lo), "v"(hi));
    return r;
}

// jax.nn.gelu approximate=True, paired f32x2 (R11-proven):
// gelu(x) = x / (1 + exp2(x*(-2.30220824 - 0.102942496 x^2)))
__device__ __forceinline__ f32x2 gelu2v(f32x2 x) {
    f32x2 x2 = x * x;
    f32x2 u = x2 * (-0.102942496f) + (f32x2){-2.30220824f, -2.30220824f};
    f32x2 t = x * u;
    f32x2 e;
    e.x = __builtin_amdgcn_exp2f(t.x);
    e.y = __builtin_amdgcn_exp2f(t.y);
    f32x2 d = e + 1.0f;
    f32x2 r;
    r.x = __builtin_amdgcn_rcpf(d.x);
    r.y = __builtin_amdgcn_rcpf(d.y);
    return x * r;
}

// gelu on an f32x4 -> packed 4x bf16 (u32x2)
__device__ __forceinline__ u32x2 gelu4_pk(f32x4 c) {
    f32x2 g01 = gelu2v((f32x2){c[0], c[1]});
    f32x2 g23 = gelu2v((f32x2){c[2], c[3]});
    u32x2 pv;
    pv.x = cvt_pk_bf16(g01.x, g01.y);
    pv.y = cvt_pk_bf16(g23.x, g23.y);
    return pv;
}

// ---------------- weight packing into MFMA fragment layout (bf16) ----------------
// Fragment f (1KB): lane l supplies W[k0+j][col16 + (l&15)], k0 = s*32 + (l>>4)*8.
//   f in [0,16):    W0, nt = f
//   f in [16,144):  W1, f = 16 + nt*8 + s      (nt-major: per-wave 16KB contiguous)
//   f in [144,176): W2, f = 144 + c*8 + s      (c = output 16-col block 0..3)
__global__ void pack_w(const float* __restrict__ W0, const float* __restrict__ W1,
                       const float* __restrict__ W2, unsigned short* __restrict__ wp) {
    int tid = blockIdx.x * blockDim.x + threadIdx.x;
    if (tid >= 176 * 64) return;
    int fid = tid >> 6, l = tid & 63, ln = l & 15, lg = l >> 4;
    unsigned short v[8];
    if (fid < 16) {
        int nt = fid, k0 = lg * 8;
        #pragma unroll
        for (int j = 0; j < 8; ++j) {
            int k = k0 + j;
            v[j] = f2bf(k < 6 ? W0[k * 256 + nt * 16 + ln] : 0.0f);
        }
    } else if (fid < 144) {
        int g = fid - 16;
        int nt = g >> 3, s = g & 7;
        int col = nt * 16 + ln;
        int k0 = s * 32 + lg * 8;
        #pragma unroll
        for (int j = 0; j < 8; ++j) v[j] = f2bf(W1[(k0 + j) * 256 + col]);
    } else {
        int g = fid - 144;
        int c = g >> 3, s = g & 7;
        int col = c * 16 + ln;
        int k0 = s * 32 + lg * 8;
        #pragma unroll
        for (int j = 0; j < 8; ++j) v[j] = f2bf(W2[(k0 + j) * 64 + col]);
    }
    unsigned short* o = &wp[tid * 8];
    #pragma unroll
    for (int j = 0; j < 8; ++j) o[j] = v[j];
}

// ---------------- fused GNO kernel (transposed GEMMs: D = W^T * act^T) -------------
// R11 structure + T2 XOR-swizzle on h_lds: colbyte ^= ((row&7)<<4) on BOTH the
// write and read side (row = mt*16+ln so the XOR value is thread-constant
// (ln&7)<<4). Breaks the (ln+lg)%8 slot-group collapse of the 33-slot row
// stride (SQ_LDS_BANK_CONFLICT 3.57e7).
__global__ __launch_bounds__(512, 4)
void gno_fused(const float* __restrict__ y, const float* __restrict__ x,
               const float* __restrict__ f_y, const int* __restrict__ nbr,
               const float* __restrict__ wts,
               const float* __restrict__ b0, const float* __restrict__ b1,
               const float* __restrict__ b2,
               const unsigned short* __restrict__ wp,
               float* __restrict__ out) {
    __shared__ __align__(16) unsigned short agg_lds[TM * AGG_STRIDE];  // 10.2 KB
    __shared__ __align__(16) unsigned short h_lds[TM * H_STRIDE];      // 67.6 KB

    const int b = blockIdx.x;
    const int tid = threadIdx.x;
    const int l = tid & 63;
    const int w = tid >> 6;          // wave 0..7
    const int wm = w & 1;            // edge half (GEMM3/epilogue)
    const int wc = w >> 1;           // c-tile 0..3 (GEMM3/epilogue)
    const int lg = l >> 4;
    const int ln = l & 15;
    const int xorv = (ln & 7) << 4;  // h_lds swizzle (row&7)<<4, row = mt*16+ln
    const int ebase = b * TM;

    // weight base pointers (contiguous per-wave fragment runs)
    const char* wpb = (const char*)wp;
    const char* pW0 = wpb + w * 2048 + l * 16;             // nt=2w at +0, 2w+1 at +1024
    const char* pW1 = wpb + 16384 + w * 16384 + l * 16;    // (n,s) at + n*8192 + s*1024
    const char* pW2 = wpb + 147456 + wc * 8192 + l * 16;   // s at + s*1024
    // LDS bases
    const char* aggb = (const char*)agg_lds + ln * 80 + lg * 16;   // mt at +mt*1280
    char* hrow = (char*)h_lds + ln * 528;                  // + mt*8448 + (colbyte^xorv)
    const int cwb = w * 64 + lg * 8;                       // write colbyte base (+n*32)
    const int crb = lg * 16;                               // read colbyte base (+s*64)

    // ---- stage agg = [y[nbr[e]] (3), x[e>>5] (3), 0...] as bf16, K padded to 32
    if (tid < TM) {
        int e = ebase + tid;
        int j = nbr[e];
        int i = e >> 5;              // uniform CSR: row_splits = arange*32
        const float* yr = &y[j * 3];
        const float* xr = &x[i * 3];
        u32x4 q0;
        q0.x = cvt_pk_bf16(yr[0], yr[1]);
        q0.y = cvt_pk_bf16(yr[2], xr[0]);
        q0.z = cvt_pk_bf16(xr[1], xr[2]);
        q0.w = 0u;
        u32x4 z = {0u, 0u, 0u, 0u};
        unsigned short* row = &agg_lds[tid * AGG_STRIDE];
        *(u32x4*)(row +  0) = q0;
        *(u32x4*)(row +  8) = z;
        *(u32x4*)(row + 16) = z;
        *(u32x4*)(row + 24) = z;
    }
    __syncthreads();

    // ---- GEMM1: h0^T = gelu(W0^T @ agg^T + b0); wave w: ntiles {2w,2w+1} x 8 mt
    {
        short8 aw0 = *(const short8*)(pW0);
        short8 aw1 = *(const short8*)(pW0 + 1024);
        f32x4 b0f0 = *(const f32x4*)&b0[(2 * w) * 16 + lg * 4];
        f32x4 b0f1 = *(const f32x4*)&b0[(2 * w + 1) * 16 + lg * 4];
        #pragma unroll
        for (int mt = 0; mt < 8; ++mt) {
            short8 ag = *(const short8*)(aggb + mt * 1280);
            f32x4 c0 = __builtin_amdgcn_mfma_f32_16x16x32_bf16(aw0, ag, b0f0, 0, 0, 0);
            f32x4 c1 = __builtin_amdgcn_mfma_f32_16x16x32_bf16(aw1, ag, b0f1, 0, 0, 0);
            *(u32x2*)(hrow + mt * 8448 + ((cwb) ^ xorv))      = gelu4_pk(c0);
            *(u32x2*)(hrow + mt * 8448 + ((cwb + 32) ^ xorv)) = gelu4_pk(c1);
        }
    }
    __syncthreads();

    // ---- GEMM2: h1^T = gelu(W1^T @ h0^T + b1), K=256; acc[8 mt][2 nt] (AGPR)
    f32x4 acc[8][2];
    {
        f32x4 b1f0 = *(const f32x4*)&b1[(2 * w) * 16 + lg * 4];
        f32x4 b1f1 = *(const f32x4*)&b1[(2 * w + 1) * 16 + lg * 4];
        #pragma unroll
        for (int mt = 0; mt < 8; ++mt) { acc[mt][0] = b1f0; acc[mt][1] = b1f1; }
    }
    #pragma unroll
    for (int s = 0; s < 8; ++s) {
        short8 aw0 = *(const short8*)(pW1 + s * 1024);
        short8 aw1 = *(const short8*)(pW1 + 8192 + s * 1024);
        const int cr = (crb + s * 64) ^ xorv;
        #pragma unroll
        for (int mt = 0; mt < 8; ++mt) {
            short8 hb = *(const short8*)(hrow + mt * 8448 + cr);
            acc[mt][0] = __builtin_amdgcn_mfma_f32_16x16x32_bf16(aw0, hb, acc[mt][0], 0, 0, 0);
            acc[mt][1] = __builtin_amdgcn_mfma_f32_16x16x32_bf16(aw1, hb, acc[mt][1], 0, 0, 0);
        }
    }
    __syncthreads();   // all waves done READING h0 before overwriting with h1

    #pragma unroll
    for (int mt = 0; mt < 8; ++mt) {
        #pragma unroll
        for (int n = 0; n < 2; ++n) {
            *(u32x2*)(hrow + mt * 8448 + ((cwb + n * 32) ^ xorv)) = gelu4_pk(acc[mt][n]);
        }
    }
    __syncthreads();

    // ---- prefetch f_y / wts for epilogue (latency hides under GEMM3's MFMAs)
    f32x4 fy[4];
    float wv[4];
    #pragma unroll
    for (int m = 0; m < 4; ++m) {
        int e = ebase + (wm * 4 + m) * 16 + ln;
        int j = nbr[e];
        fy[m] = *(const f32x4*)&f_y[j * 64 + wc * 16 + lg * 4];
        wv[m] = wts[e];
    }

    // ---- GEMM3: rep^T = W2^T @ h1^T + b2; wave: 4 mt (edge half) x 1 c-tile
    f32x4 acc3[4];
    {
        f32x4 b2f = *(const f32x4*)&b2[wc * 16 + lg * 4];
        #pragma unroll
        for (int m = 0; m < 4; ++m) acc3[m] = b2f;
    }
    char* hrow3 = hrow + wm * 33792;   // wm*4 mt offset (4*8448)
    #pragma unroll
    for (int s = 0; s < 8; ++s) {
        short8 aw = *(const short8*)(pW2 + s * 1024);
        const int cr = (crb + s * 64) ^ xorv;
        #pragma unroll
        for (int m = 0; m < 4; ++m) {
            short8 hb = *(const short8*)(hrow3 + m * 8448 + cr);
            acc3[m] = __builtin_amdgcn_mfma_f32_16x16x32_bf16(aw, hb, acc3[m], 0, 0, 0);
        }
    }

    // ---- epilogue: rep * f_y[nbr] * wts, segment-sum (32 edges per out row)
    {
        f32x4 seg[2];
        seg[0] = (f32x4){0.f, 0.f, 0.f, 0.f};
        seg[1] = (f32x4){0.f, 0.f, 0.f, 0.f};
        #pragma unroll
        for (int m = 0; m < 4; ++m) {
            f32x4 v;
            #pragma unroll
            for (int i = 0; i < 4; ++i)
                v[i] = acc3[m][i] * fy[m][i] * wv[m];
            seg[m >> 1] += v;
        }
        #pragma unroll
        for (int g = 0; g < 2; ++g) {
            f32x4 v = seg[g];
            #pragma unroll
            for (int d = 1; d <= 8; d <<= 1) {
                #pragma unroll
                for (int i = 0; i < 4; ++i)
                    v[i] += __shfl_xor(v[i], d, 64);
            }
            if (ln == 0)
                *(f32x4*)&out[(b * 4 + wm * 2 + g) * 64 + wc * 16 + lg * 4] = v;
        }
    }
}

extern "C" void kernel_launch(void* const* d_in, const int* in_sizes, int n_in,
                              void* d_out, int out_size, void* d_ws, size_t ws_size,
                              hipStream_t stream) {
    const float* y   = (const float*)d_in[0];
    const float* x   = (const float*)d_in[1];
    const float* f_y = (const float*)d_in[2];
    const int*   nbr = (const int*)d_in[3];
    // d_in[4] = neighbors_row_splits (uniform arange*32) -- unused
    const float* wts = (const float*)d_in[5];
    const float* W0  = (const float*)d_in[6];
    const float* b0  = (const float*)d_in[7];
    const float* W1  = (const float*)d_in[8];
    const float* b1  = (const float*)d_in[9];
    const float* W2  = (const float*)d_in[10];
    const float* b2  = (const float*)d_in[11];
    unsigned short* wp = (unsigned short*)d_ws;   // 176 KB packed bf16 fragments
    float* out = (float*)d_out;

    pack_w<<<dim3(44), dim3(256), 0, stream>>>(W0, W1, W2, wp);
    gno_fused<<<dim3(NEDGES / TM), dim3(512), 0, stream>>>(
        y, x, f_y, nbr, wts, b0, b1, b2, wp, out);
}

// Round 18
// 252.068 us; speedup vs baseline: 1.4114x; 1.4114x over previous
//
#include <hip/hip_runtime.h>
#include <hip/hip_bf16.h>
#include <stdint.h>

#define NPTS 32768
#define KNBR 32
#define NEDGES (NPTS * KNBR)
#define TM 128          // edges per block (= 4 output rows), 512 threads / 8 waves
#define AGG_STRIDE 40   // bf16 elems per agg row (80 B)
#define H_STRIDE 264    // bf16 elems per h row (528 B)

typedef __attribute__((ext_vector_type(8))) short short8;
typedef __attribute__((ext_vector_type(4))) short s16x4;
typedef __attribute__((ext_vector_type(4))) float f32x4;
typedef __attribute__((ext_vector_type(2))) float f32x2;
typedef __attribute__((ext_vector_type(4))) unsigned int u32x4;
typedef __attribute__((ext_vector_type(2))) unsigned int u32x2;

// K=16 MFMA availability (GEMM1 only; zero-pad K=32 fallback = exact R11 path)
#if __has_builtin(__builtin_amdgcn_mfma_f32_16x16x16_bf16)
  #define MFMA16(a, b, c) __builtin_amdgcn_mfma_f32_16x16x16_bf16(a, b, c, 0, 0, 0)
  #define HAVE_K16 1
#elif __has_builtin(__builtin_amdgcn_mfma_f32_16x16x16bf16_1k)
  #define MFMA16(a, b, c) __builtin_amdgcn_mfma_f32_16x16x16bf16_1k(a, b, c, 0, 0, 0)
  #define HAVE_K16 1
#else
  #define HAVE_K16 0
#endif

// round-to-nearest-even f32 -> bf16 (one-time pack kernel only)
__device__ __forceinline__ unsigned short f2bf(float f) {
    unsigned int u = __float_as_uint(f);
    unsigned int r = (u + 0x7FFFu + ((u >> 16) & 1u)) >> 16;
    return (unsigned short)r;
}

// gfx950 packed f32->bf16 (RNE), single instruction (proven)
__device__ __forceinline__ unsigned int cvt_pk_bf16(float lo, float hi) {
    unsigned int r;
    asm("v_cvt_pk_bf16_f32 %0, %1, %2" : "=v"(r) : "v"(lo), "v"(hi));
    return r;
}

// jax.nn.gelu approximate=True, paired f32x2 (R11-proven):
// gelu(x) = x / (1 + exp2(x*(-2.30220824 - 0.102942496 x^2)))
__device__ __forceinline__ f32x2 gelu2v(f32x2 x) {
    f32x2 x2 = x * x;
    f32x2 u = x2 * (-0.102942496f) + (f32x2){-2.30220824f, -2.30220824f};
    f32x2 t = x * u;
    f32x2 e;
    e.x = __builtin_amdgcn_exp2f(t.x);
    e.y = __builtin_amdgcn_exp2f(t.y);
    f32x2 d = e + 1.0f;
    f32x2 r;
    r.x = __builtin_amdgcn_rcpf(d.x);
    r.y = __builtin_amdgcn_rcpf(d.y);
    return x * r;
}

// gelu on an f32x4 -> packed 4x bf16 (u32x2)
__device__ __forceinline__ u32x2 gelu4_pk(f32x4 c) {
    f32x2 g01 = gelu2v((f32x2){c[0], c[1]});
    f32x2 g23 = gelu2v((f32x2){c[2], c[3]});
    u32x2 pv;
    pv.x = cvt_pk_bf16(g01.x, g01.y);
    pv.y = cvt_pk_bf16(g23.x, g23.y);
    return pv;
}

// ---------------- weight packing into MFMA fragment layout (bf16) ----------------
// Fragment f (1KB): lane l supplies W[k0+j][col16 + (l&15)], k0 = s*32 + (l>>4)*8.
//   f in [0,16):    W0, nt = f   (k>=6 zero-padded; the k=8..15 region doubles as
//                                 the zero source for the K16 A-fragment read)
//   f in [16,144):  W1, f = 16 + nt*8 + s      (nt-major: per-wave 16KB contiguous)
//   f in [144,176): W2, f = 144 + c*8 + s      (c = output 16-col block 0..3)
__global__ void pack_w(const float* __restrict__ W0, const float* __restrict__ W1,
                       const float* __restrict__ W2, unsigned short* __restrict__ wp) {
    int tid = blockIdx.x * blockDim.x + threadIdx.x;
    if (tid >= 176 * 64) return;
    int fid = tid >> 6, l = tid & 63, ln = l & 15, lg = l >> 4;
    unsigned short v[8];
    if (fid < 16) {
        int nt = fid, k0 = lg * 8;
        #pragma unroll
        for (int j = 0; j < 8; ++j) {
            int k = k0 + j;
            v[j] = f2bf(k < 6 ? W0[k * 256 + nt * 16 + ln] : 0.0f);
        }
    } else if (fid < 144) {
        int g = fid - 16;
        int nt = g >> 3, s = g & 7;
        int col = nt * 16 + ln;
        int k0 = s * 32 + lg * 8;
        #pragma unroll
        for (int j = 0; j < 8; ++j) v[j] = f2bf(W1[(k0 + j) * 256 + col]);
    } else {
        int g = fid - 144;
        int c = g >> 3, s = g & 7;
        int col = c * 16 + ln;
        int k0 = s * 32 + lg * 8;
        #pragma unroll
        for (int j = 0; j < 8; ++j) v[j] = f2bf(W2[(k0 + j) * 64 + col]);
    }
    unsigned short* o = &wp[tid * 8];
    #pragma unroll
    for (int j = 0; j < 8; ++j) o[j] = v[j];
}

// ---------------- fused GNO kernel (transposed GEMMs: D = W^T * act^T) -------------
// R11 structure (best measured: 284us rocprof). 8 waves. GEMM1/2: wave w owns
// ntiles {2w, 2w+1} x ALL 8 edge-tiles. GEMM3/epilogue: wave w owns edge half
// wm=w&1 (4 mt) x c-tile wc=w>>1. f_y/wts prefetched before GEMM3.
// GEMM1 runs at K=16 when the builtin exists (halves its MFMA cycles; operands
// read straight out of the K32 packing / zero-pad regions).
__global__ __launch_bounds__(512, 4)
void gno_fused(const float* __restrict__ y, const float* __restrict__ x,
               const float* __restrict__ f_y, const int* __restrict__ nbr,
               const float* __restrict__ wts,
               const float* __restrict__ b0, const float* __restrict__ b1,
               const float* __restrict__ b2,
               const unsigned short* __restrict__ wp,
               float* __restrict__ out) {
    __shared__ __align__(16) unsigned short agg_lds[TM * AGG_STRIDE];  // 10.2 KB
    __shared__ __align__(16) unsigned short h_lds[TM * H_STRIDE];      // 67.6 KB

    const int b = blockIdx.x;
    const int tid = threadIdx.x;
    const int l = tid & 63;
    const int w = tid >> 6;          // wave 0..7
    const int wm = w & 1;            // edge half (GEMM3/epilogue)
    const int wc = w >> 1;           // c-tile 0..3 (GEMM3/epilogue)
    const int lg = l >> 4;
    const int ln = l & 15;
    const int ebase = b * TM;

    // weight base pointers (contiguous per-wave fragment runs)
    const char* wpb = (const char*)wp;
    const char* pW0 = wpb + w * 2048 + l * 16;             // nt=2w at +0, 2w+1 at +1024
    const char* pW1 = wpb + 16384 + w * 16384 + l * 16;    // (n,s) at + n*8192 + s*1024
    const char* pW2 = wpb + 147456 + wc * 8192 + l * 16;   // s at + s*1024
    // LDS byte bases
    const char* aggb = (const char*)agg_lds + ln * 80 + lg * 16;      // mt at +mt*1280
    char* hwb = (char*)h_lds + ln * 528 + w * 64 + lg * 8;            // (mt,n): +mt*8448+n*32
    const char* hrb = (const char*)h_lds + ln * 528 + lg * 16;        // (mt,s): +mt*8448+s*64

    // ---- stage agg = [y[nbr[e]] (3), x[e>>5] (3), 0...] as bf16, K padded to 32
    if (tid < TM) {
        int e = ebase + tid;
        int j = nbr[e];
        int i = e >> 5;              // uniform CSR: row_splits = arange*32
        const float* yr = &y[j * 3];
        const float* xr = &x[i * 3];
        u32x4 q0;
        q0.x = cvt_pk_bf16(yr[0], yr[1]);
        q0.y = cvt_pk_bf16(yr[2], xr[0]);
        q0.z = cvt_pk_bf16(xr[1], xr[2]);
        q0.w = 0u;
        u32x4 z = {0u, 0u, 0u, 0u};
        unsigned short* row = &agg_lds[tid * AGG_STRIDE];
        *(u32x4*)(row +  0) = q0;
        *(u32x4*)(row +  8) = z;
        *(u32x4*)(row + 16) = z;
        *(u32x4*)(row + 24) = z;
    }
    __syncthreads();

    // ---- GEMM1: h0^T = gelu(W0^T @ agg^T + b0); wave w: ntiles {2w,2w+1} x 8 mt
#if HAVE_K16
    {
        // K16 A-operand straight from the K32-W0 packing:
        // lg 0/1 -> lane(0,ln)'s two 8B halves (k0-3, k4-7);
        // lg 2/3 -> lane(1,ln)'s halves = W0's zero-padded k8-15 region.
        const char* a16 = wpb + w * 2048 + ((lg >> 1) * 16 + ln) * 16 + (lg & 1) * 8;
        s16x4 aw0 = *(const s16x4*)(a16);
        s16x4 aw1 = *(const s16x4*)(a16 + 1024);
        f32x4 b0f0 = *(const f32x4*)&b0[(2 * w) * 16 + lg * 4];
        f32x4 b0f1 = *(const f32x4*)&b0[(2 * w + 1) * 16 + lg * 4];
        // K16 B-operand from agg rows: bytes [lg*8, +8); lg>=2 hits the zero pad.
        const char* ag16 = (const char*)agg_lds + ln * 80 + lg * 8;
        #pragma unroll
        for (int mt = 0; mt < 8; ++mt) {
            s16x4 ag = *(const s16x4*)(ag16 + mt * 1280);
            f32x4 c0 = MFMA16(aw0, ag, b0f0);
            f32x4 c1 = MFMA16(aw1, ag, b0f1);
            *(u32x2*)(hwb + mt * 8448)      = gelu4_pk(c0);
            *(u32x2*)(hwb + mt * 8448 + 32) = gelu4_pk(c1);
        }
    }
#else
    {
        short8 aw0 = *(const short8*)(pW0);
        short8 aw1 = *(const short8*)(pW0 + 1024);
        f32x4 b0f0 = *(const f32x4*)&b0[(2 * w) * 16 + lg * 4];
        f32x4 b0f1 = *(const f32x4*)&b0[(2 * w + 1) * 16 + lg * 4];
        #pragma unroll
        for (int mt = 0; mt < 8; ++mt) {
            short8 ag = *(const short8*)(aggb + mt * 1280);
            f32x4 c0 = __builtin_amdgcn_mfma_f32_16x16x32_bf16(aw0, ag, b0f0, 0, 0, 0);
            f32x4 c1 = __builtin_amdgcn_mfma_f32_16x16x32_bf16(aw1, ag, b0f1, 0, 0, 0);
            *(u32x2*)(hwb + mt * 8448)      = gelu4_pk(c0);
            *(u32x2*)(hwb + mt * 8448 + 32) = gelu4_pk(c1);
        }
    }
#endif
    __syncthreads();

    // ---- GEMM2: h1^T = gelu(W1^T @ h0^T + b1), K=256; acc[8 mt][2 nt] (AGPR)
    f32x4 acc[8][2];
    {
        f32x4 b1f0 = *(const f32x4*)&b1[(2 * w) * 16 + lg * 4];
        f32x4 b1f1 = *(const f32x4*)&b1[(2 * w + 1) * 16 + lg * 4];
        #pragma unroll
        for (int mt = 0; mt < 8; ++mt) { acc[mt][0] = b1f0; acc[mt][1] = b1f1; }
    }
    #pragma unroll
    for (int s = 0; s < 8; ++s) {
        short8 aw0 = *(const short8*)(pW1 + s * 1024);
        short8 aw1 = *(const short8*)(pW1 + 8192 + s * 1024);
        #pragma unroll
        for (int mt = 0; mt < 8; ++mt) {
            short8 hb = *(const short8*)(hrb + mt * 8448 + s * 64);
            acc[mt][0] = __builtin_amdgcn_mfma_f32_16x16x32_bf16(aw0, hb, acc[mt][0], 0, 0, 0);
            acc[mt][1] = __builtin_amdgcn_mfma_f32_16x16x32_bf16(aw1, hb, acc[mt][1], 0, 0, 0);
        }
    }
    __syncthreads();   // all waves done READING h0 before overwriting with h1

    #pragma unroll
    for (int mt = 0; mt < 8; ++mt) {
        #pragma unroll
        for (int n = 0; n < 2; ++n) {
            *(u32x2*)(hwb + mt * 8448 + n * 32) = gelu4_pk(acc[mt][n]);
        }
    }
    __syncthreads();

    // ---- prefetch f_y / wts for epilogue (latency hides under GEMM3's MFMAs)
    f32x4 fy[4];
    float wv[4];
    #pragma unroll
    for (int m = 0; m < 4; ++m) {
        int e = ebase + (wm * 4 + m) * 16 + ln;
        int j = nbr[e];
        fy[m] = *(const f32x4*)&f_y[j * 64 + wc * 16 + lg * 4];
        wv[m] = wts[e];
    }

    // ---- GEMM3: rep^T = W2^T @ h1^T + b2; wave: 4 mt (edge half) x 1 c-tile
    f32x4 acc3[4];
    {
        f32x4 b2f = *(const f32x4*)&b2[wc * 16 + lg * 4];
        #pragma unroll
        for (int m = 0; m < 4; ++m) acc3[m] = b2f;
    }
    const char* hrb3 = hrb + wm * 33792;   // wm*4 mt offset (4*8448)
    #pragma unroll
    for (int s = 0; s < 8; ++s) {
        short8 aw = *(const short8*)(pW2 + s * 1024);
        #pragma unroll
        for (int m = 0; m < 4; ++m) {
            short8 hb = *(const short8*)(hrb3 + m * 8448 + s * 64);
            acc3[m] = __builtin_amdgcn_mfma_f32_16x16x32_bf16(aw, hb, acc3[m], 0, 0, 0);
        }
    }

    // ---- epilogue: rep * f_y[nbr] * wts, segment-sum (32 edges per out row)
    {
        f32x4 seg[2];
        seg[0] = (f32x4){0.f, 0.f, 0.f, 0.f};
        seg[1] = (f32x4){0.f, 0.f, 0.f, 0.f};
        #pragma unroll
        for (int m = 0; m < 4; ++m) {
            f32x4 v;
            #pragma unroll
            for (int i = 0; i < 4; ++i)
                v[i] = acc3[m][i] * fy[m][i] * wv[m];
            seg[m >> 1] += v;
        }
        #pragma unroll
        for (int g = 0; g < 2; ++g) {
            f32x4 v = seg[g];
            #pragma unroll
            for (int d = 1; d <= 8; d <<= 1) {
                #pragma unroll
                for (int i = 0; i < 4; ++i)
                    v[i] += __shfl_xor(v[i], d, 64);
            }
            if (ln == 0)
                *(f32x4*)&out[(b * 4 + wm * 2 + g) * 64 + wc * 16 + lg * 4] = v;
        }
    }
}

extern "C" void kernel_launch(void* const* d_in, const int* in_sizes, int n_in,
                              void* d_out, int out_size, void* d_ws, size_t ws_size,
                              hipStream_t stream) {
    const float* y   = (const float*)d_in[0];
    const float* x   = (const float*)d_in[1];
    const float* f_y = (const float*)d_in[2];
    const int*   nbr = (const int*)d_in[3];
    // d_in[4] = neighbors_row_splits (uniform arange*32) -- unused
    const float* wts = (const float*)d_in[5];
    const float* W0  = (const float*)d_in[6];
    const float* b0  = (const float*)d_in[7];
    const float* W1  = (const float*)d_in[8];
    const float* b1  = (const float*)d_in[9];
    const float* W2  = (const float*)d_in[10];
    const float* b2  = (const float*)d_in[11];
    unsigned short* wp = (unsigned short*)d_ws;   // 176 KB packed bf16 fragments
    float* out = (float*)d_out;

    pack_w<<<dim3(44), dim3(256), 0, stream>>>(W0, W1, W2, wp);
    gno_fused<<<dim3(NEDGES / TM), dim3(512), 0, stream>>>(
        y, x, f_y, nbr, wts, b0, b1, b2, wp, out);
}